// Round 9
// baseline (433.957 us; speedup 1.0000x reference)
//
#include <hip/hip_runtime.h>
#include <cstdint>

#define NITEMS   100000
#define BROWS    512
#define DDIM     64
#define S_BLOCKS 391        // phase-1 item-blocks (256 items each)
#define IPB      256
#define NCHUNKS  782        // fallback chunks of 128 items
#define FB_Y     8
#define SURV_CAP 512        // per-row survivor capacity (mean 247, +17 sigma)
#define RNG_BLKS 1024
#define NELEM    51200000u
#define OUT_FEAT 512
#define OUT_LOSS (512 + 512 * 64)
#define OUT_MSIM (OUT_LOSS + 1)

// Gumbel filter: g monotone in bits; bits >= T <=> g may exceed 6.0.
#define BITS_RAW_T 4284334592u
#define G_TE       6.001f

typedef __attribute__((ext_vector_type(8)))  short  bf16x8;
typedef __attribute__((ext_vector_type(16))) float  f32x16;
typedef unsigned long long u64;
typedef uint32_t u32;

#define ROTL(x, r) __builtin_amdgcn_alignbit((x), (x), 32u - (r))

// ---------------- Threefry-2x32-20, key=(0,42). VERIFIED R4 (absmax 0.0):
// partitionable scheme, counters (hi=0, lo=e), output = bits1 ^ bits2.
__device__ __forceinline__ u32 threefry_0_42_xor(u32 e) {
    const u32 K1 = 42u;
    const u32 K2 = 0x1BD11BDAu ^ 42u;   // K0 = 0
    u32 x0 = 0u;
    u32 x1 = e + K1;
#define TFR(r) { x0 += x1; x1 = ROTL(x1, r) ^ x0; }
    TFR(13u) TFR(15u) TFR(26u) TFR(6u)
    x0 += K1;  x1 += K2 + 1u;
    TFR(17u) TFR(29u) TFR(16u) TFR(24u)
    x0 += K2;  x1 += 2u;
    TFR(13u) TFR(15u) TFR(26u) TFR(6u)
    x1 += K1 + 3u;
    TFR(17u) TFR(29u) TFR(16u) TFR(24u)
    x0 += K1;  x1 += K2 + 4u;
    TFR(13u) TFR(15u) TFR(26u) TFR(6u)
    x0 += K2;  x1 += 5u;
#undef TFR
    return x0 ^ x1;
}

__device__ __forceinline__ float gumbel_from_bits(u32 b) {   // precise logf REQUIRED
    float f = __uint_as_float((b >> 9) | 0x3F800000u) - 1.0f;
    f = fmaxf(f, 1.17549435e-38f);
    return -logf(-logf(f));
}
__device__ __forceinline__ u32 order_map(float v) {
    u32 x = __float_as_uint(v);
    return (x & 0x80000000u) ? ~x : (x | 0x80000000u);
}
__device__ __forceinline__ short f32_to_bf16_rne(float f) {
    u32 b = __float_as_uint(f);
    u32 r = (b + 0x7FFFu + ((b >> 16) & 1u)) >> 16;
    return (short)r;
}
__device__ __forceinline__ float bf16_to_f32(short h) {
    return __uint_as_float(((u32)(uint16_t)h) << 16);
}

// ---------------- K1: prep = uif GEMM (W^T in LDS) + norms + zero state ----
__global__ void prep_kernel(const float* __restrict__ UF, const float* __restrict__ W,
                            const float* __restrict__ bias, const float* __restrict__ A,
                            float* __restrict__ uif, float* __restrict__ unorm,
                            float* __restrict__ wsAM4, int* __restrict__ cnt,
                            int* __restrict__ done, int* __restrict__ rowcnt,
                            float* __restrict__ out) {
    const int t = threadIdx.x, b = blockIdx.x;
    if (b == 0) {
        if (t == 0) { *cnt = 0; out[OUT_LOSS] = 0.f; out[OUT_MSIM] = 0.f; }
        done[t] = 0; done[t + 256] = 0;
        rowcnt[t] = 0; rowcnt[t + 256] = 0;
    }
    if (b < 128) {
        __shared__ float Wt[128 * 65];
        for (int i = t; i < 8192; i += 256) {
            int d = i >> 7, k = i & 127;
            Wt[k * 65 + d] = W[i];
        }
        __syncthreads();
        const int row = b * 4 + (t >> 6);
        const int d   = t & 63;
        const float* u = UF + row * 128;
        float s = 0.f;
#pragma unroll 4
        for (int k = 0; k < 128; k++) s = fmaf(u[k], Wt[k * 65 + d], s);
        s += bias[d];
        uif[row * 64 + d] = s;
        float q = s * s;
#pragma unroll
        for (int o = 32; o >= 1; o >>= 1) q += __shfl_xor(q, o);
        if (d == 0) unorm[row] = sqrtf(q);
    } else {
        const int item = (b - 128) * 256 + t;
        float q = 0.f;
        if (item < NITEMS) {
            const float4* r = (const float4*)(A + (size_t)item * DDIM);
#pragma unroll
            for (int k = 0; k < 16; k++) {
                float4 x = r[k];
                q = fmaf(x.x, x.x, q); q = fmaf(x.y, x.y, q);
                q = fmaf(x.z, x.z, q); q = fmaf(x.w, x.w, q);
            }
        }
        float n = sqrtf(q);
#pragma unroll
        for (int o = 32; o >= 1; o >>= 1) n = fmaxf(n, __shfl_xor(n, o));
        if ((t & 63) == 0) wsAM4[(b - 128) * 4 + (t >> 6)] = n;
    }
}

// ---------------- K2: fused = {phase1 MFMA s~max blocks} + {rng sweep blocks}
// Interleaved in one grid so MFMA/LDS-bound waves and pure-VALU rng waves
// co-schedule on each CU (m114: pipes overlap).
__global__ __launch_bounds__(256, 4) void fused_kernel(
        const float* __restrict__ A, const float* __restrict__ uif,
        float* __restrict__ wsSM, u64* __restrict__ surv, int* __restrict__ rowcnt) {
    __shared__ bf16x8 sh_ah[4 * 64];
    __shared__ bf16x8 sh_al[4 * 64];
    const int bx  = blockIdx.x;
    const int tid = threadIdx.x;

    int pidx = -1, ridx = -1;
    if (bx < 2048) { if (bx & 1) ridx = bx >> 1; else pidx = bx >> 1; }
    else pidx = 1024 + (bx - 2048);

    if (ridx >= 0) {
        // ---- rng sweep: pure threefry, survivors to per-row lists ----
        const u32 stride = RNG_BLKS * 256u;
        for (u32 e = (u32)ridx * 256u + (u32)tid; e < NELEM; e += stride) {
            u32 b = threefry_0_42_xor(e);
            if (b >= BITS_RAW_T) {                       // ~0.25%
                u32 row  = (u32)(((u64)e * 1407374884ull) >> 47);  // e/100000
                u32 item = e - row * 100000u;
                u32 slot = atomicAdd(&rowcnt[row], 1);
                if (slot < SURV_CAP)
                    surv[row * SURV_CAP + slot] = ((u64)b << 32) | (u64)item;
            }
        }
        return;
    }

    // ---- phase1: MFMA 3-term bf16 score, track s~max per (row, sb) ----
    const int lane = tid & 63;
    const int wv   = tid >> 6;
    const int sb   = pidx >> 2;
    const int rg   = pidx & 3;
    const int itembase = sb * IPB;
    const int ntiles = min(8, (NITEMS - itembase + 31) >> 5);
    const int row   = rg * 128 + wv * 32 + (lane & 31);
    const int khalf = (lane >> 5) * 8;

    bf16x8 uh[4], ul[4];
#pragma unroll
    for (int s = 0; s < 4; s++) {
        const float* src = uif + row * 64 + khalf + 16 * s;
        float4 v0 = *(const float4*)src;
        float4 v1 = *(const float4*)(src + 4);
        float vv[8] = {v0.x, v0.y, v0.z, v0.w, v1.x, v1.y, v1.z, v1.w};
        bf16x8 h, l2;
#pragma unroll
        for (int j = 0; j < 8; j++) {
            short hh = f32_to_bf16_rne(vv[j]);
            float r  = vv[j] - bf16_to_f32(hh);
            h[j] = hh; l2[j] = f32_to_bf16_rne(r);
        }
        uh[s] = h; ul[s] = l2;
    }

    float sm = -3.0e38f;
    const int s_i   = tid & 31;
    const int s_c   = tid >> 5;
    const int s_dst = (s_c >> 1) * 64 + s_i + 32 * (s_c & 1);   // R7-verified map
    const float* s_srcbase = A + (size_t)s_i * 64 + 8 * s_c;

    float4 p0 = *(const float4*)(s_srcbase + (size_t)itembase * 64);
    float4 p1 = *(const float4*)(s_srcbase + (size_t)itembase * 64 + 4);

    for (int t = 0; t < ntiles; t++) {
        const int tb = itembase + t * 32;
        bf16x8 h, l2;
        {
            float vv[8] = {p0.x, p0.y, p0.z, p0.w, p1.x, p1.y, p1.z, p1.w};
#pragma unroll
            for (int j = 0; j < 8; j++) {
                short hh = f32_to_bf16_rne(vv[j]);
                float r  = vv[j] - bf16_to_f32(hh);
                h[j] = hh; l2[j] = f32_to_bf16_rne(r);
            }
        }
        __syncthreads();
        sh_ah[s_dst] = h; sh_al[s_dst] = l2;
        __syncthreads();
        if (t + 1 < ntiles) {
            const float* src = s_srcbase + (size_t)(tb + 32) * 64;
            p0 = *(const float4*)src;
            p1 = *(const float4*)(src + 4);
        }

        f32x16 acc;
#pragma unroll
        for (int z = 0; z < 16; z++) acc[z] = 0.0f;
#pragma unroll
        for (int s = 0; s < 4; s++) {
            bf16x8 ah = sh_ah[s * 64 + lane];
            bf16x8 al = sh_al[s * 64 + lane];
            acc = __builtin_amdgcn_mfma_f32_32x32x16_bf16(ah, uh[s], acc, 0, 0, 0);
            acc = __builtin_amdgcn_mfma_f32_32x32x16_bf16(al, uh[s], acc, 0, 0, 0);
            acc = __builtin_amdgcn_mfma_f32_32x32x16_bf16(ah, ul[s], acc, 0, 0, 0);
        }
#pragma unroll
        for (int i = 0; i < 16; i++) sm = fmaxf(sm, acc[i]);
    }

    sm = fmaxf(sm, __shfl_xor(sm, 32));
    if (lane < 32) wsSM[(size_t)row * S_BLOCKS + sb] = sm;
}

// ---------------- K3: certify = survivor scoring + gap test + resolve ------
__global__ void certify_kernel(const float* __restrict__ wsSM, const float* __restrict__ wsAM4,
                               const float* __restrict__ unorm, const float* __restrict__ uif,
                               const float* __restrict__ A, const u64* __restrict__ surv,
                               const int* __restrict__ rowcnt, const int* __restrict__ need_replace,
                               u64* __restrict__ packed, int* __restrict__ rowlist,
                               int* __restrict__ cnt, float* __restrict__ out) {
    const int row = blockIdx.x, t = threadIdx.x;      // 64 threads
    __shared__ float Us[64];
    Us[t] = uif[row * 64 + t];
    __syncthreads();

    float am = 0.f;
    for (int i = t; i < S_BLOCKS * 4; i += 64) am = fmaxf(am, wsAM4[i]);
    float smx = -3.0e38f;
    for (int i = t; i < S_BLOCKS; i += 64) smx = fmaxf(smx, wsSM[(size_t)row * S_BLOCKS + i]);

    const int n = min(rowcnt[row], SURV_CAP);
    u64 p1 = 0ull; float f1 = -3.0e38f, f2 = -3.0e38f;
    for (int i = t; i < n; i += 64) {
        u64 en   = surv[row * SURV_CAP + i];
        u32 item = (u32)(en & 0xFFFFFFFFull);
        float g  = gumbel_from_bits((u32)(en >> 32));
        const float4* a4 = (const float4*)(A + (size_t)item * DDIM);
        float s0 = 0.f, s1 = 0.f;
#pragma unroll
        for (int k = 0; k < 16; k += 2) {
            float4 x = a4[k];
            float4 y = a4[k + 1];
            s0 = fmaf(x.x, Us[4*k    ], s0);
            s0 = fmaf(x.y, Us[4*k + 1], s0);
            s0 = fmaf(x.z, Us[4*k + 2], s0);
            s0 = fmaf(x.w, Us[4*k + 3], s0);
            s1 = fmaf(y.x, Us[4*k + 4], s1);
            s1 = fmaf(y.y, Us[4*k + 5], s1);
            s1 = fmaf(y.z, Us[4*k + 6], s1);
            s1 = fmaf(y.w, Us[4*k + 7], s1);
        }
        float v = (s0 + s1) + g;
        if (v > f1) {
            f2 = f1; f1 = v;
            p1 = ((u64)order_map(v) << 32) | (u32)(~item);
        } else f2 = fmaxf(f2, v);
    }
#pragma unroll
    for (int off = 1; off < 64; off <<= 1) {
        u64   op  = __shfl_xor(p1, off);
        float of1 = __shfl_xor(f1, off);
        float of2 = __shfl_xor(f2, off);
        am  = fmaxf(am,  __shfl_xor(am,  off));
        smx = fmaxf(smx, __shfl_xor(smx, off));
        if (op > p1) { f2 = fmaxf(fmaxf(f1, of2), f2); p1 = op; f1 = of1; }
        else         { f2 = fmaxf(f2, fmaxf(of1, of2)); }
    }

    const float bound = fmaxf(f2, smx + G_TE);
    const float E = 1.5e-4f * unorm[row] * am + 3.0e-5f;   // R6-verified margin
    if (f1 - bound > 2.0f * E) {
        const int idx = (int)(~(u32)(p1 & 0xFFFFFFFFull));
        float fr = A[(size_t)idx * DDIM + t];
        out[OUT_FEAT + row * DDIM + t] = fr;
        int   item = need_replace[2 * row + 1];
        float fa   = A[(size_t)item * DDIM + t];
        float dot = fa * fr, na2 = fa * fa, nb2 = fr * fr;
#pragma unroll
        for (int o = 32; o >= 1; o >>= 1) {
            dot += __shfl_down(dot, o);
            na2 += __shfl_down(na2, o);
            nb2 += __shfl_down(nb2, o);
        }
        if (t == 0) {
            out[row] = (float)idx;
            float denom = fmaxf(sqrtf(na2) * sqrtf(nb2), 1e-6f);
            float sim = (dot / denom + 1.0f) * 0.5f;
            float d = sim - 0.5f;
            atomicAdd(&out[OUT_LOSS], d * d * (1.0f / 512.0f));
            atomicAdd(&out[OUT_MSIM], sim * (1.0f / 512.0f));
        }
    } else if (t == 0) {
        packed[row] = 0ull;
        rowlist[atomicAdd(cnt, 1)] = row;
    }
}

// ---------------- K4: exact f32 fallback; finishing block resolves row -----
__global__ void fallback_kernel(const float* __restrict__ A, const float* __restrict__ uif,
                                const int* __restrict__ rowlist, const int* __restrict__ cnt,
                                const int* __restrict__ need_replace,
                                u64* __restrict__ packed, int* __restrict__ done,
                                float* __restrict__ out) {
    __shared__ float As[128 * 65];
    __shared__ float Us[64];
    __shared__ int   sh_last;
    const int t  = threadIdx.x;          // 0..127
    const int c  = blockIdx.x;
    const int n0 = c * 128;
    const int nitem = min(128, NITEMS - n0);
    const int total = *cnt;
    if ((int)blockIdx.y >= total) return;

    if (t < nitem) {
        const float4* src = (const float4*)(A + (size_t)(n0 + t) * 64);
#pragma unroll
        for (int k4 = 0; k4 < 16; k4++) {
            float4 x = src[k4];
            As[t * 65 + 4 * k4 + 0] = x.x; As[t * 65 + 4 * k4 + 1] = x.y;
            As[t * 65 + 4 * k4 + 2] = x.z; As[t * 65 + 4 * k4 + 3] = x.w;
        }
    }
    for (int li = blockIdx.y; li < total; li += FB_Y) {
        const int row = rowlist[li];
        __syncthreads();
        if (t < 64) Us[t] = uif[row * 64 + t];
        __syncthreads();
        u64 pk = 0ull;
        if (t < nitem) {
            const int item = n0 + t;
            u32 rb  = threefry_0_42_xor((u32)row * (u32)NITEMS + (u32)item);
            float g = gumbel_from_bits(rb);
            float s0 = 0.f, s1 = 0.f;
#pragma unroll
            for (int k8 = 0; k8 < 64; k8 += 8) {   // R5-verified op order
                s0 = fmaf(As[t * 65 + k8 + 0], Us[k8 + 0], s0);
                s0 = fmaf(As[t * 65 + k8 + 1], Us[k8 + 1], s0);
                s0 = fmaf(As[t * 65 + k8 + 2], Us[k8 + 2], s0);
                s0 = fmaf(As[t * 65 + k8 + 3], Us[k8 + 3], s0);
                s1 = fmaf(As[t * 65 + k8 + 4], Us[k8 + 4], s1);
                s1 = fmaf(As[t * 65 + k8 + 5], Us[k8 + 5], s1);
                s1 = fmaf(As[t * 65 + k8 + 6], Us[k8 + 6], s1);
                s1 = fmaf(As[t * 65 + k8 + 7], Us[k8 + 7], s1);
            }
            float v = (s0 + s1) + g;
            pk = ((u64)order_map(v) << 32) | (u32)(~(u32)item);
        }
#pragma unroll
        for (int off = 1; off < 64; off <<= 1) {
            u64 o = __shfl_xor(pk, off);
            pk = (o > pk) ? o : pk;
        }
        if ((t & 63) == 0) atomicMax(&packed[row], pk);
        __syncthreads();
        if (t == 0) {
            __threadfence();
            sh_last = (atomicAdd(&done[li], 1) == NCHUNKS - 1) ? 1 : 0;
        }
        __syncthreads();
        if (sh_last && t < 64) {
            u64 fin = atomicMax(&packed[row], 0ull);
            const int idx = (int)(~(u32)(fin & 0xFFFFFFFFull));
            float fr = A[(size_t)idx * DDIM + t];
            out[OUT_FEAT + row * DDIM + t] = fr;
            int   item = need_replace[2 * row + 1];
            float fa   = A[(size_t)item * DDIM + t];
            float dot = fa * fr, na2 = fa * fa, nb2 = fr * fr;
#pragma unroll
            for (int o = 32; o >= 1; o >>= 1) {
                dot += __shfl_down(dot, o);
                na2 += __shfl_down(na2, o);
                nb2 += __shfl_down(nb2, o);
            }
            if (t == 0) {
                out[row] = (float)idx;
                float denom = fmaxf(sqrtf(na2) * sqrtf(nb2), 1e-6f);
                float sim = (dot / denom + 1.0f) * 0.5f;
                float d = sim - 0.5f;
                atomicAdd(&out[OUT_LOSS], d * d * (1.0f / 512.0f));
                atomicAdd(&out[OUT_MSIM], sim * (1.0f / 512.0f));
            }
        }
        __syncthreads();
    }
}

extern "C" void kernel_launch(void* const* d_in, const int* in_sizes, int n_in,
                              void* d_out, int out_size, void* d_ws, size_t ws_size,
                              hipStream_t stream) {
    (void)in_sizes; (void)n_in; (void)out_size; (void)ws_size;
    const int*   need_replace = (const int*)d_in[0];
    const float* UF           = (const float*)d_in[1];
    const float* A            = (const float*)d_in[2];
    const float* W            = (const float*)d_in[3];
    const float* bias         = (const float*)d_in[4];
    float* out = (float*)d_out;

    char* ws = (char*)d_ws;                              // ~2.91 MB total
    float* wsSM    = (float*)(ws);                       // 512*391*4 = 800768
    u64*   surv    = (u64*)  (ws + 800768);              // 512*512*8 = 2097152
    float* uif     = (float*)(ws + 2897920);             // 131072
    u64*   packed  = (u64*)  (ws + 3028992);             // 4096
    float* unorm   = (float*)(ws + 3033088);             // 2048
    float* wsAM4   = (float*)(ws + 3035136);             // 6256
    int*   rowlist = (int*)  (ws + 3041392);             // 2048
    int*   cnt     = (int*)  (ws + 3043440);             // 4
    int*   done    = (int*)  (ws + 3043444);             // 2048
    int*   rowcnt  = (int*)  (ws + 3045492);             // 2048

    prep_kernel<<<519, 256, 0, stream>>>(UF, W, bias, A, uif, unorm, wsAM4,
                                         cnt, done, rowcnt, out);
    fused_kernel<<<2588, 256, 0, stream>>>(A, uif, wsSM, surv, rowcnt);
    certify_kernel<<<BROWS, 64, 0, stream>>>(wsSM, wsAM4, unorm, uif, A, surv, rowcnt,
                                             need_replace, packed, rowlist, cnt, out);
    fallback_kernel<<<dim3(NCHUNKS, FB_Y), 128, 0, stream>>>(A, uif, rowlist, cnt,
                                                             need_replace, packed, done, out);
}

// Round 10
// 257.520 us; speedup vs baseline: 1.6851x; 1.6851x over previous
//
#include <hip/hip_runtime.h>
#include <cstdint>

#define NITEMS   100000
#define BROWS    512
#define DDIM     64
#define S_BLOCKS 391        // phase-1 item-blocks (256 items each)
#define IPB      256
#define FB_X     64         // fallback item-chunks (1568 items each)
#define FB_Y     8
#define FB_CHUNK 1568
#define OUT_FEAT 512
#define OUT_LOSS (512 + 512 * 64)
#define OUT_MSIM (OUT_LOSS + 1)

// Gumbel filter: g monotone in bits; bits >= T <=> g may exceed 6.0.
#define BITS_RAW_T 4284334592u
#define G_TE       6.001f

typedef __attribute__((ext_vector_type(8)))  short  bf16x8;
typedef __attribute__((ext_vector_type(16))) float  f32x16;
typedef unsigned long long u64;
typedef uint32_t u32;

#define ROTL(x, r) __builtin_amdgcn_alignbit((x), (x), 32u - (r))

// ---------------- Threefry-2x32-20, key=(0,42). VERIFIED R4 (absmax 0.0):
// partitionable scheme, counters (hi=0, lo=e), output = bits1 ^ bits2.
__device__ __forceinline__ u32 threefry_0_42_xor(u32 e) {
    const u32 K1 = 42u;
    const u32 K2 = 0x1BD11BDAu ^ 42u;   // K0 = 0
    u32 x0 = 0u;
    u32 x1 = e + K1;
#define TFR(r) { x0 += x1; x1 = ROTL(x1, r) ^ x0; }
    TFR(13u) TFR(15u) TFR(26u) TFR(6u)
    x0 += K1;  x1 += K2 + 1u;
    TFR(17u) TFR(29u) TFR(16u) TFR(24u)
    x0 += K2;  x1 += 2u;
    TFR(13u) TFR(15u) TFR(26u) TFR(6u)
    x1 += K1 + 3u;
    TFR(17u) TFR(29u) TFR(16u) TFR(24u)
    x0 += K1;  x1 += K2 + 4u;
    TFR(13u) TFR(15u) TFR(26u) TFR(6u)
    x0 += K2;  x1 += 5u;
#undef TFR
    return x0 ^ x1;
}

// Two independent chains interleaved: guarantees ILP 2 on the serial
// threefry dependency chain (R8 disasm evidence: compiler serialized chains).
__device__ __forceinline__ void threefry_pair(u32 ea, u32 eb, u32& oa, u32& ob) {
    const u32 K1 = 42u;
    const u32 K2 = 0x1BD11BDAu ^ 42u;
    u32 a0 = 0u, a1 = ea + K1;
    u32 b0 = 0u, b1 = eb + K1;
#define TFR2(r) { a0 += a1; b0 += b1; a1 = ROTL(a1, r) ^ a0; b1 = ROTL(b1, r) ^ b0; }
    TFR2(13u) TFR2(15u) TFR2(26u) TFR2(6u)
    a0 += K1; a1 += K2 + 1u;  b0 += K1; b1 += K2 + 1u;
    TFR2(17u) TFR2(29u) TFR2(16u) TFR2(24u)
    a0 += K2; a1 += 2u;       b0 += K2; b1 += 2u;
    TFR2(13u) TFR2(15u) TFR2(26u) TFR2(6u)
    a1 += K1 + 3u;            b1 += K1 + 3u;
    TFR2(17u) TFR2(29u) TFR2(16u) TFR2(24u)
    a0 += K1; a1 += K2 + 4u;  b0 += K1; b1 += K2 + 4u;
    TFR2(13u) TFR2(15u) TFR2(26u) TFR2(6u)
    a0 += K2; a1 += 5u;       b0 += K2; b1 += 5u;
#undef TFR2
    oa = a0 ^ a1; ob = b0 ^ b1;
}

__device__ __forceinline__ float gumbel_from_bits(u32 b) {   // precise logf REQUIRED
    float f = __uint_as_float((b >> 9) | 0x3F800000u) - 1.0f;
    f = fmaxf(f, 1.17549435e-38f);
    return -logf(-logf(f));
}
__device__ __forceinline__ u32 order_map(float v) {
    u32 x = __float_as_uint(v);
    return (x & 0x80000000u) ? ~x : (x | 0x80000000u);
}
__device__ __forceinline__ float unpack_val(u64 p) {
    u32 x = (u32)(p >> 32);
    u32 f = (x & 0x80000000u) ? (x & 0x7FFFFFFFu) : ~x;
    return __uint_as_float(f);
}
__device__ __forceinline__ short f32_to_bf16_rne(float f) {
    u32 b = __float_as_uint(f);
    u32 r = (b + 0x7FFFu + ((b >> 16) & 1u)) >> 16;
    return (short)r;
}
__device__ __forceinline__ float bf16_to_f32(short h) {
    return __uint_as_float(((u32)(uint16_t)h) << 16);
}

// ---------------- K1: prep = uif GEMM (W^T in LDS) + norms + zero state ----
__global__ void prep_kernel(const float* __restrict__ UF, const float* __restrict__ W,
                            const float* __restrict__ bias, const float* __restrict__ A,
                            float* __restrict__ uif, float* __restrict__ unorm,
                            float* __restrict__ wsAM4, int* __restrict__ cnt,
                            int* __restrict__ done, float* __restrict__ out) {
    const int t = threadIdx.x, b = blockIdx.x;
    if (b == 0) {
        if (t == 0) { *cnt = 0; out[OUT_LOSS] = 0.f; out[OUT_MSIM] = 0.f; }
        done[t] = 0; done[t + 256] = 0;
    }
    if (b < 128) {
        __shared__ float Wt[128 * 65];
        for (int i = t; i < 8192; i += 256) {
            int d = i >> 7, k = i & 127;
            Wt[k * 65 + d] = W[i];
        }
        __syncthreads();
        const int row = b * 4 + (t >> 6);
        const int d   = t & 63;
        const float* u = UF + row * 128;
        float s = 0.f;
#pragma unroll 4
        for (int k = 0; k < 128; k++) s = fmaf(u[k], Wt[k * 65 + d], s);
        s += bias[d];
        uif[row * 64 + d] = s;
        float q = s * s;
#pragma unroll
        for (int o = 32; o >= 1; o >>= 1) q += __shfl_xor(q, o);
        if (d == 0) unorm[row] = sqrtf(q);
    } else {
        const int item = (b - 128) * 256 + t;
        float q = 0.f;
        if (item < NITEMS) {
            const float4* r = (const float4*)(A + (size_t)item * DDIM);
#pragma unroll
            for (int k = 0; k < 16; k++) {
                float4 x = r[k];
                q = fmaf(x.x, x.x, q); q = fmaf(x.y, x.y, q);
                q = fmaf(x.z, x.z, q); q = fmaf(x.w, x.w, q);
            }
        }
        float n = sqrtf(q);
#pragma unroll
        for (int o = 32; o >= 1; o >>= 1) n = fmaxf(n, __shfl_xor(n, o));
        if ((t & 63) == 0) wsAM4[(b - 128) * 4 + (t >> 6)] = n;
    }
}

// ---------------- K2: phase-1 MFMA score + filtered gumbel + top-2 ---------
// launch_bounds(256,6): grid 1564 at 6 blocks/CU cap -> near-full single-batch
// residency (~6 waves/SIMD) to hide the threefry dep chain; 84-VGPR budget.
__global__ __launch_bounds__(256, 6) void phase1_kernel(
        const float* __restrict__ A, const float* __restrict__ uif,
        u64* __restrict__ wsT1, float* __restrict__ wsB) {
    __shared__ bf16x8 sh_ah[4 * 64];
    __shared__ bf16x8 sh_al[4 * 64];
    const int tid  = threadIdx.x;
    const int lane = tid & 63;
    const int wv   = tid >> 6;
    const int rg   = blockIdx.y;
    const int sb   = blockIdx.x;
    const int itembase = sb * IPB;
    const int ntiles = min(8, (NITEMS - itembase + 31) >> 5);
    const int row   = rg * 128 + wv * 32 + (lane & 31);
    const int khalf = (lane >> 5) * 8;

    bf16x8 uh[4], ul[4];
#pragma unroll
    for (int s = 0; s < 4; s++) {
        const float* src = uif + row * 64 + khalf + 16 * s;
        float4 v0 = *(const float4*)src;
        float4 v1 = *(const float4*)(src + 4);
        float vv[8] = {v0.x, v0.y, v0.z, v0.w, v1.x, v1.y, v1.z, v1.w};
        bf16x8 h, l2;
#pragma unroll
        for (int j = 0; j < 8; j++) {
            short hh = f32_to_bf16_rne(vv[j]);
            float r  = vv[j] - bf16_to_f32(hh);
            h[j] = hh; l2[j] = f32_to_bf16_rne(r);
        }
        uh[s] = h; ul[s] = l2;
    }

    u64 t1p = 0ull; float t1f = -3.0e38f, t2f = -3.0e38f, sm = -3.0e38f;
    const u32 rowbase_e = (u32)row * (u32)NITEMS;

    const int s_i   = tid & 31;
    const int s_c   = tid >> 5;
    const int s_dst = (s_c >> 1) * 64 + s_i + 32 * (s_c & 1);   // R7-verified map
    const float* s_srcbase = A + (size_t)s_i * 64 + 8 * s_c;

    float4 p0 = *(const float4*)(s_srcbase + (size_t)itembase * 64);
    float4 p1 = *(const float4*)(s_srcbase + (size_t)itembase * 64 + 4);

    for (int t = 0; t < ntiles; t++) {
        const int tb = itembase + t * 32;
        bf16x8 h, l2;
        {
            float vv[8] = {p0.x, p0.y, p0.z, p0.w, p1.x, p1.y, p1.z, p1.w};
#pragma unroll
            for (int j = 0; j < 8; j++) {
                short hh = f32_to_bf16_rne(vv[j]);
                float r  = vv[j] - bf16_to_f32(hh);
                h[j] = hh; l2[j] = f32_to_bf16_rne(r);
            }
        }
        __syncthreads();
        sh_ah[s_dst] = h; sh_al[s_dst] = l2;
        __syncthreads();
        if (t + 1 < ntiles) {
            const float* src = s_srcbase + (size_t)(tb + 32) * 64;
            p0 = *(const float4*)src;
            p1 = *(const float4*)(src + 4);
        }

        f32x16 acc;
#pragma unroll
        for (int z = 0; z < 16; z++) acc[z] = 0.0f;
#pragma unroll
        for (int s = 0; s < 4; s++) {
            bf16x8 ah = sh_ah[s * 64 + lane];
            bf16x8 al = sh_al[s * 64 + lane];
            acc = __builtin_amdgcn_mfma_f32_32x32x16_bf16(ah, uh[s], acc, 0, 0, 0);
            acc = __builtin_amdgcn_mfma_f32_32x32x16_bf16(al, uh[s], acc, 0, 0, 0);
            acc = __builtin_amdgcn_mfma_f32_32x32x16_bf16(ah, ul[s], acc, 0, 0, 0);
        }

        const int ib4 = tb + 4 * (lane >> 5);
#pragma unroll
        for (int i = 0; i < 16; i += 2) {
            const int il0 = (i & 3) + 8 * (i >> 2);
            const int il1 = ((i + 1) & 3) + 8 * ((i + 1) >> 2);
            const int item0 = ib4 + il0;
            const int item1 = ib4 + il1;
            u32 r0, r1;
            threefry_pair(rowbase_e + (u32)item0, rowbase_e + (u32)item1, r0, r1);
            float sA = acc[i], sB = acc[i + 1];
            sm = fmaxf(sm, fmaxf(sA, sB));
            if (r0 >= BITS_RAW_T) {               // ~0.25% of items
                float v = sA + gumbel_from_bits(r0);
                if (v > t1f) {
                    t2f = t1f; t1f = v;
                    t1p = ((u64)order_map(v) << 32) | (u32)(~(u32)item0);
                } else t2f = fmaxf(t2f, v);
            }
            if (r1 >= BITS_RAW_T) {
                float v = sB + gumbel_from_bits(r1);
                if (v > t1f) {
                    t2f = t1f; t1f = v;
                    t1p = ((u64)order_map(v) << 32) | (u32)(~(u32)item1);
                } else t2f = fmaxf(t2f, v);
            }
        }
    }

    float bnd = fmaxf(t2f, sm + G_TE);
    {
        u64   op = __shfl_xor(t1p, 32);
        float of = __shfl_xor(t1f, 32);
        float ob = __shfl_xor(bnd, 32);
        if (op > t1p) { bnd = fmaxf(fmaxf(bnd, ob), t1f); t1p = op; t1f = of; }
        else          { bnd = fmaxf(fmaxf(bnd, ob), of); }
    }
    if (lane < 32) {
        wsT1[(size_t)row * S_BLOCKS + sb] = t1p;
        wsB [(size_t)row * S_BLOCKS + sb] = bnd;
    }
}

// ---------------- K3: merge + certify; certified rows resolved inline ------
__global__ void merge_kernel(const u64* __restrict__ wsT1, const float* __restrict__ wsB,
                             const float* __restrict__ wsAM4, const float* __restrict__ unorm,
                             const float* __restrict__ A, const int* __restrict__ need_replace,
                             u64* __restrict__ packed, int* __restrict__ rowlist,
                             int* __restrict__ cnt, float* __restrict__ out) {
    const int row = blockIdx.x, t = threadIdx.x;     // 64 threads
    float am = 0.f;
    for (int i = t; i < S_BLOCKS * 4; i += 64) am = fmaxf(am, wsAM4[i]);
    u64 p1 = 0ull; float f1 = -3.0e38f, f2 = -3.0e38f;
    for (int sbk = t; sbk < S_BLOCKS; sbk += 64) {
        u64   ep = wsT1[(size_t)row * S_BLOCKS + sbk];
        float e2 = wsB [(size_t)row * S_BLOCKS + sbk];
        if (ep > p1) { f2 = fmaxf(fmaxf(f1, e2), f2); p1 = ep; f1 = unpack_val(ep); }
        else         { float v = unpack_val(ep); f2 = fmaxf(f2, fmaxf(v, e2)); }
    }
#pragma unroll
    for (int off = 1; off < 64; off <<= 1) {
        u64   op  = __shfl_xor(p1, off);
        float of1 = __shfl_xor(f1, off);
        float of2 = __shfl_xor(f2, off);
        am = fmaxf(am, __shfl_xor(am, off));
        if (op > p1) { f2 = fmaxf(fmaxf(f1, of2), f2); p1 = op; f1 = of1; }
        else         { f2 = fmaxf(f2, fmaxf(of1, of2)); }
    }
    const float E = 1.5e-4f * unorm[row] * am + 3.0e-5f;   // R6-verified margin
    if (f1 - f2 > 2.0f * E) {
        const int idx = (int)(~(u32)(p1 & 0xFFFFFFFFull));
        float fr = A[(size_t)idx * DDIM + t];
        out[OUT_FEAT + row * DDIM + t] = fr;
        int   item = need_replace[2 * row + 1];
        float fa   = A[(size_t)item * DDIM + t];
        float dot = fa * fr, na2 = fa * fa, nb2 = fr * fr;
#pragma unroll
        for (int o = 32; o >= 1; o >>= 1) {
            dot += __shfl_down(dot, o);
            na2 += __shfl_down(na2, o);
            nb2 += __shfl_down(nb2, o);
        }
        if (t == 0) {
            out[row] = (float)idx;
            float denom = fmaxf(sqrtf(na2) * sqrtf(nb2), 1e-6f);
            float sim = (dot / denom + 1.0f) * 0.5f;
            float d = sim - 0.5f;
            atomicAdd(&out[OUT_LOSS], d * d * (1.0f / 512.0f));
            atomicAdd(&out[OUT_MSIM], sim * (1.0f / 512.0f));
        }
    } else if (t == 0) {
        packed[row] = 0ull;
        rowlist[atomicAdd(cnt, 1)] = row;
    }
}

// ---------------- K4: exact f32 fallback (512 blocks); last block resolves -
__global__ void fallback_kernel(const float* __restrict__ A, const float* __restrict__ uif,
                                const int* __restrict__ rowlist, const int* __restrict__ cnt,
                                const int* __restrict__ need_replace,
                                u64* __restrict__ packed, int* __restrict__ done,
                                float* __restrict__ out) {
    __shared__ float Us[64];
    __shared__ int   sh_last;
    const int t  = threadIdx.x;          // 0..255
    const int xb = blockIdx.x;           // 0..63
    const int total = *cnt;
    const int iend = min((xb + 1) * FB_CHUNK, NITEMS);

    for (int li = blockIdx.y; li < total; li += FB_Y) {
        const int row = rowlist[li];
        __syncthreads();
        if (t < 64) Us[t] = uif[row * 64 + t];
        __syncthreads();
        u64 pk = 0ull;
        for (int item = xb * FB_CHUNK + t; item < iend; item += 256) {
            u32 rb  = threefry_0_42_xor((u32)row * (u32)NITEMS + (u32)item);
            float g = gumbel_from_bits(rb);
            const float4* a4 = (const float4*)(A + (size_t)item * DDIM);
            float s0 = 0.f, s1 = 0.f;
#pragma unroll
            for (int k = 0; k < 16; k += 2) {     // R5-verified op order
                float4 x = a4[k];
                float4 y = a4[k + 1];
                s0 = fmaf(x.x, Us[4*k    ], s0);
                s0 = fmaf(x.y, Us[4*k + 1], s0);
                s0 = fmaf(x.z, Us[4*k + 2], s0);
                s0 = fmaf(x.w, Us[4*k + 3], s0);
                s1 = fmaf(y.x, Us[4*k + 4], s1);
                s1 = fmaf(y.y, Us[4*k + 5], s1);
                s1 = fmaf(y.z, Us[4*k + 6], s1);
                s1 = fmaf(y.w, Us[4*k + 7], s1);
            }
            float v = (s0 + s1) + g;
            u64 c = ((u64)order_map(v) << 32) | (u32)(~(u32)item);
            pk = (c > pk) ? c : pk;
        }
#pragma unroll
        for (int off = 1; off < 64; off <<= 1) {
            u64 o = __shfl_xor(pk, off);
            pk = (o > pk) ? o : pk;
        }
        if ((t & 63) == 0) atomicMax(&packed[row], pk);
        __syncthreads();
        if (t == 0) {
            __threadfence();
            sh_last = (atomicAdd(&done[li], 1) == FB_X - 1) ? 1 : 0;
        }
        __syncthreads();
        if (sh_last && t < 64) {               // last contributor resolves row
            u64 fin = atomicMax(&packed[row], 0ull);   // coherent read
            const int idx = (int)(~(u32)(fin & 0xFFFFFFFFull));
            float fr = A[(size_t)idx * DDIM + t];
            out[OUT_FEAT + row * DDIM + t] = fr;
            int   item = need_replace[2 * row + 1];
            float fa   = A[(size_t)item * DDIM + t];
            float dot = fa * fr, na2 = fa * fa, nb2 = fr * fr;
#pragma unroll
            for (int o = 32; o >= 1; o >>= 1) {
                dot += __shfl_down(dot, o);
                na2 += __shfl_down(na2, o);
                nb2 += __shfl_down(nb2, o);
            }
            if (t == 0) {
                out[row] = (float)idx;
                float denom = fmaxf(sqrtf(na2) * sqrtf(nb2), 1e-6f);
                float sim = (dot / denom + 1.0f) * 0.5f;
                float d = sim - 0.5f;
                atomicAdd(&out[OUT_LOSS], d * d * (1.0f / 512.0f));
                atomicAdd(&out[OUT_MSIM], sim * (1.0f / 512.0f));
            }
        }
        __syncthreads();
    }
}

extern "C" void kernel_launch(void* const* d_in, const int* in_sizes, int n_in,
                              void* d_out, int out_size, void* d_ws, size_t ws_size,
                              hipStream_t stream) {
    (void)in_sizes; (void)n_in; (void)out_size; (void)ws_size;
    const int*   need_replace = (const int*)d_in[0];
    const float* UF           = (const float*)d_in[1];
    const float* A            = (const float*)d_in[2];
    const float* W            = (const float*)d_in[3];
    const float* bias         = (const float*)d_in[4];
    float* out = (float*)d_out;

    char* ws = (char*)d_ws;                              // ~2.55 MB total
    u64*   wsT1    = (u64*)  (ws);                       // 1601536
    float* wsB     = (float*)(ws + 1601536);             // 800768
    float* uif     = (float*)(ws + 2402304);             // 131072
    u64*   packed  = (u64*)  (ws + 2533376);             // 4096
    float* unorm   = (float*)(ws + 2537472);             // 2048
    float* wsAM4   = (float*)(ws + 2539520);             // 6256
    int*   rowlist = (int*)  (ws + 2545776);             // 2048
    int*   cnt     = (int*)  (ws + 2547824);             // 4
    int*   done    = (int*)  (ws + 2547828);             // 2048

    prep_kernel<<<519, 256, 0, stream>>>(UF, W, bias, A, uif, unorm, wsAM4, cnt, done, out);
    phase1_kernel<<<dim3(S_BLOCKS, 4), 256, 0, stream>>>(A, uif, wsT1, wsB);
    merge_kernel<<<BROWS, 64, 0, stream>>>(wsT1, wsB, wsAM4, unorm, A, need_replace,
                                           packed, rowlist, cnt, out);
    fallback_kernel<<<dim3(FB_X, FB_Y), 256, 0, stream>>>(A, uif, rowlist, cnt,
                                                          need_replace, packed, done, out);
}